// Round 6
// baseline (378.272 us; speedup 1.0000x reference)
//
#include <hip/hip_runtime.h>

// RawISPProcessing: demosaic (bilinear 2x; flips are no-ops under the
// symmetric half-pixel grid) + folded (x2 * chflip * awb^T * ccm^T * chflip)
// 3x3 matrix + clip + gamma 1/2.2.
//
// R6: R5's wave-row structure (wave == one full 512-px source row, 8 px/lane,
// two output rows/thread, plain f4 stores) but NO cross-lane shfl: each lane
// loads its halo columns itself via 4 aligned f32x4 chunks per channel-row
// (i-4, i, i+4, i+8; clamped at edges). R5's 16 DS ops sat in the per-channel
// dependency chain (load -> blend -> shfl -> lgkm wait -> blend) and at
// 4 waves/SIMD didn't hide: R5 halved VMEM vs R2 yet ran ~8us slower.
// Halo chunks are L1-hits (same lines as neighbors' mains) -> HBM unchanged.

#define GAMMA_INV 0.45454545454545453f
#define EPS_CLIP 1e-8f

typedef float f32x4 __attribute__((ext_vector_type(4)));

__device__ __forceinline__ float gamma_enc(float v) {
  v = fmaxf(v, EPS_CLIP);
  return exp2f(GAMMA_INV * __log2f(v));
}

// One channel: 3 src rows, 10-col window [i-1 .. i+8] built from 4 aligned f4
// chunks per row (no cross-lane ops). Vertical blend -> e[10] (top), o[10]
// (bot); horizontal 2x -> top[16], bot[16].
__device__ __forceinline__ void up2_row8(const float* __restrict__ ch,
                                         int jm, int j, int jp,
                                         int i, int ilm, int irp, int lane,
                                         float top[16], float bot[16]) {
  const int W = 512;
  const float* r0 = ch + jm * W;
  const float* r1 = ch + j  * W;
  const float* r2 = ch + jp * W;
  // 12 independent loads — issue together, no DS in the chain.
  f32x4 La = *reinterpret_cast<const f32x4*>(r0 + ilm);
  f32x4 Ma = *reinterpret_cast<const f32x4*>(r0 + i);
  f32x4 Na = *reinterpret_cast<const f32x4*>(r0 + i + 4);
  f32x4 Ra = *reinterpret_cast<const f32x4*>(r0 + irp);
  f32x4 Lb = *reinterpret_cast<const f32x4*>(r1 + ilm);
  f32x4 Mb = *reinterpret_cast<const f32x4*>(r1 + i);
  f32x4 Nb = *reinterpret_cast<const f32x4*>(r1 + i + 4);
  f32x4 Rb = *reinterpret_cast<const f32x4*>(r1 + irp);
  f32x4 Lc = *reinterpret_cast<const f32x4*>(r2 + ilm);
  f32x4 Mc = *reinterpret_cast<const f32x4*>(r2 + i);
  f32x4 Nc = *reinterpret_cast<const f32x4*>(r2 + i + 4);
  f32x4 Rc = *reinterpret_cast<const f32x4*>(r2 + irp);

  bool l0 = (lane == 0), l63 = (lane == 63);
  // Window index 0 = col i-1, 1..8 = cols i..i+7, 9 = col i+8 (edge-clamped).
  float A[10]  = {l0 ? Ma.x : La.w, Ma.x, Ma.y, Ma.z, Ma.w,
                  Na.x, Na.y, Na.z, Na.w, l63 ? Na.w : Ra.x};
  float Bv[10] = {l0 ? Mb.x : Lb.w, Mb.x, Mb.y, Mb.z, Mb.w,
                  Nb.x, Nb.y, Nb.z, Nb.w, l63 ? Nb.w : Rb.x};
  float Cv[10] = {l0 ? Mc.x : Lc.w, Mc.x, Mc.y, Mc.z, Mc.w,
                  Nc.x, Nc.y, Nc.z, Nc.w, l63 ? Nc.w : Rc.x};

  float e[10], o[10];
#pragma unroll
  for (int c = 0; c < 10; ++c) {
    e[c] = 0.25f * A[c]  + 0.75f * Bv[c];   // even output row
    o[c] = 0.75f * Bv[c] + 0.25f * Cv[c];   // odd output row
  }
#pragma unroll
  for (int p = 0; p < 8; ++p) {
    top[2 * p]     = 0.25f * e[p] + 0.75f * e[p + 1];
    top[2 * p + 1] = 0.75f * e[p + 1] + 0.25f * e[p + 2];
    bot[2 * p]     = 0.25f * o[p] + 0.75f * o[p + 1];
    bot[2 * p + 1] = 0.75f * o[p + 1] + 0.25f * o[p + 2];
  }
}

__global__ __launch_bounds__(256, 4) void isp_kernel(
    const float* __restrict__ pred, const float* __restrict__ gt,
    const float* __restrict__ awb, const float* __restrict__ ccm,
    float* __restrict__ out) {
  constexpr int H = 512, W = 512;
  constexpr int HW = H * W;
  constexpr long long OUT_IMG = 8LL * 3 * 1024 * 1024;

  int idx  = blockIdx.x * blockDim.x + threadIdx.x;  // 2*8*512*64 threads
  int tg   = idx & 63;           // col group: src cols [8tg, 8tg+7]
  int j    = (idx >> 6) & 511;   // src row
  int b    = (idx >> 15) & 7;    // batch
  int img  = idx >> 18;          // 0=pred, 1=gt
  int lane = tg;                 // wave == one full row; lane == tg

  // Folded color matrix: out[k] = 2 * sum_e v[e] * sum_c awb[2-e][c]*ccm[c][2-k]
  const float* A  = awb + b * 9;
  const float* Cm = ccm + b * 9;
  float M[3][3];
#pragma unroll
  for (int k = 0; k < 3; ++k) {
#pragma unroll
    for (int e = 0; e < 3; ++e) {
      int ar = (2 - e) * 3;
      int cc = 2 - k;
      M[k][e] = 2.0f * (A[ar + 0] * Cm[0 + cc] +
                        A[ar + 1] * Cm[3 + cc] +
                        A[ar + 2] * Cm[6 + cc]);
    }
  }

  int i   = 8 * tg;
  int ilm = (i >= 4) ? i - 4 : 0;             // left halo chunk (aligned)
  int irp = (i + 8 < W) ? i + 8 : W - 4;      // right halo chunk (aligned)
  int jm  = (j > 0) ? j - 1 : 0;
  int jp  = (j < H - 1) ? j + 1 : H - 1;

  const float* src = (img ? gt : pred) + (long long)b * 4 * HW;

  float rT[16], rB[16], gT[16], gB[16], qT[16], qB[16];
  up2_row8(src + 0 * HW, jm, j, jp, i, ilm, irp, lane, rT, rB);   // red
  up2_row8(src + 1 * HW, jm, j, jp, i, ilm, irp, lane, gT, gB);   // Gr
  up2_row8(src + 2 * HW, jm, j, jp, i, ilm, irp, lane, qT, qB);   // Gb
  // Green quad-parity combine: (ee)=avg, (eo)=Gr, (oe)=Gb, (oo)=avg.
#pragma unroll
  for (int p = 0; p < 8; ++p) {
    gT[2 * p]     = 0.5f * (gT[2 * p] + qT[2 * p]);
    /* gT[2p+1] stays Gr */
    gB[2 * p]     = qB[2 * p];
    gB[2 * p + 1] = 0.5f * (gB[2 * p + 1] + qB[2 * p + 1]);
  }
  up2_row8(src + 3 * HW, jm, j, jp, i, ilm, irp, lane, qT, qB);   // blue (reuse q)

  int oy = 2 * j, ox = 16 * tg;
  float* dst = out + (long long)img * OUT_IMG;

#pragma unroll
  for (int k = 0; k < 3; ++k) {
    float oT[16], oB[16];
#pragma unroll
    for (int p = 0; p < 16; ++p) {
      oT[p] = gamma_enc(M[k][0] * rT[p] + M[k][1] * gT[p] + M[k][2] * qT[p]);
      oB[p] = gamma_enc(M[k][0] * rB[p] + M[k][1] * gB[p] + M[k][2] * qB[p]);
    }
    long long obase = ((long long)(b * 3 + k) * 1024 + oy) * 1024 + ox;
#pragma unroll
    for (int q = 0; q < 4; ++q) {
      f32x4 vT = {oT[4 * q], oT[4 * q + 1], oT[4 * q + 2], oT[4 * q + 3]};
      f32x4 vB = {oB[4 * q], oB[4 * q + 1], oB[4 * q + 2], oB[4 * q + 3]};
      *reinterpret_cast<f32x4*>(dst + obase + 4 * q)        = vT;
      *reinterpret_cast<f32x4*>(dst + obase + 1024 + 4 * q) = vB;
    }
  }
}

extern "C" void kernel_launch(void* const* d_in, const int* in_sizes, int n_in,
                              void* d_out, int out_size, void* d_ws, size_t ws_size,
                              hipStream_t stream) {
  const float* pred = (const float*)d_in[0];
  const float* gt   = (const float*)d_in[1];
  const float* awb  = (const float*)d_in[2];
  const float* ccm  = (const float*)d_in[3];
  // d_in[4] = rgb_gain: unused by the reference.
  float* out = (float*)d_out;

  const int total = 2 * 8 * 512 * 64;  // img * batch * src-rows * col-groups
  dim3 block(256);
  dim3 grid(total / 256);
  isp_kernel<<<grid, block, 0, stream>>>(pred, gt, awb, ccm, out);
}

// Round 8
// 260.272 us; speedup vs baseline: 1.4534x; 1.4534x over previous
//
#include <hip/hip_runtime.h>

// RawISPProcessing: demosaic (bilinear 2x; flips are no-ops under the
// symmetric half-pixel grid) + folded (x2 * chflip * awb^T * ccm^T * chflip)
// 3x3 matrix + clip + gamma 1/2.2.
//
// R7b: R5 structure (wave == one full 512-px source row, 8 src px/lane, shfl
// halos, 16-B-stride loads -> FETCH 49MB) + LDS STORE-TRANSPOSE. R4b/R6
// showed ~2.5x WRITE amplification (494-553MB vs 201MB ideal) from 64-B
// lane-stride stores regardless of NT/plain. Fix: stage the wave's 2x1024
// output row in LDS and store contiguous 1KB wave bursts (lane l -> f4 at
// col 256q+4l). LDS swizzle phys = c + 4*(c>>6) keeps BOTH ds_write_b128
// and ds_read_b128 16B-aligned (R7's 17-stride read base was only 4B-aligned).

#define GAMMA_INV 0.45454545454545453f
#define EPS_CLIP 1e-8f

typedef float f32x4 __attribute__((ext_vector_type(4)));

__device__ __forceinline__ float gamma_enc(float v) {
  v = fmaxf(v, EPS_CLIP);
  return exp2f(GAMMA_INV * __log2f(v));
}

// One channel: 3 src rows x 8 cols, vertical blend -> e[8] (top), o[8] (bot);
// halos via in-wave shfl; horizontal 2x -> top[16], bot[16].
__device__ __forceinline__ void up2_row8(const float* __restrict__ ch,
                                         int jm, int j, int jp, int i, int lane,
                                         float top[16], float bot[16]) {
  const int W = 512;
  const float* r0 = ch + jm * W + i;
  const float* r1 = ch + j  * W + i;
  const float* r2 = ch + jp * W + i;
  f32x4 a0 = *reinterpret_cast<const f32x4*>(r0);
  f32x4 a1 = *reinterpret_cast<const f32x4*>(r0 + 4);
  f32x4 b0 = *reinterpret_cast<const f32x4*>(r1);
  f32x4 b1 = *reinterpret_cast<const f32x4*>(r1 + 4);
  f32x4 c0 = *reinterpret_cast<const f32x4*>(r2);
  f32x4 c1 = *reinterpret_cast<const f32x4*>(r2 + 4);
  float A[8]  = {a0.x, a0.y, a0.z, a0.w, a1.x, a1.y, a1.z, a1.w};
  float Bv[8] = {b0.x, b0.y, b0.z, b0.w, b1.x, b1.y, b1.z, b1.w};
  float Cv[8] = {c0.x, c0.y, c0.z, c0.w, c1.x, c1.y, c1.z, c1.w};
  float e[8], o[8];
#pragma unroll
  for (int c = 0; c < 8; ++c) {
    e[c] = 0.25f * A[c]  + 0.75f * Bv[c];   // even output row
    o[c] = 0.75f * Bv[c] + 0.25f * Cv[c];   // odd output row
  }
  // Halos: col 8*lane-1 == left lane's e[7]/o[7]; col 8*lane+8 == right
  // lane's e[0]/o[0]. Clamp at image edges (lane 0 / lane 63).
  float eL = __shfl_up(e[7], 1);   eL = (lane == 0)  ? e[0] : eL;
  float oL = __shfl_up(o[7], 1);   oL = (lane == 0)  ? o[0] : oL;
  float eR = __shfl_down(e[0], 1); eR = (lane == 63) ? e[7] : eR;
  float oR = __shfl_down(o[0], 1); oR = (lane == 63) ? o[7] : oR;
  top[0] = 0.25f * eL + 0.75f * e[0];
  bot[0] = 0.25f * oL + 0.75f * o[0];
#pragma unroll
  for (int p = 0; p < 7; ++p) {
    top[2 * p + 1] = 0.75f * e[p] + 0.25f * e[p + 1];
    top[2 * p + 2] = 0.25f * e[p] + 0.75f * e[p + 1];
    bot[2 * p + 1] = 0.75f * o[p] + 0.25f * o[p + 1];
    bot[2 * p + 2] = 0.25f * o[p] + 0.75f * o[p + 1];
  }
  top[15] = 0.75f * e[7] + 0.25f * eR;
  bot[15] = 0.75f * o[7] + 0.25f * oR;
}

__global__ __launch_bounds__(256) void isp_kernel(
    const float* __restrict__ pred, const float* __restrict__ gt,
    const float* __restrict__ awb, const float* __restrict__ ccm,
    float* __restrict__ out) {
  constexpr int H = 512, W = 512;
  constexpr int HW = H * W;
  constexpr long long OUT_IMG = 8LL * 3 * 1024 * 1024;

  // Per-wave transpose buffers: logical 1024-float out row at swizzled
  // phys = c + 4*(c>>6) (4-float pad per 64-float block; 16B alignment
  // preserved on both write and read). Max phys = 1023 + 4*15 = 1083 -> 1088.
  __shared__ float lds[4][2][1088];

  int idx  = blockIdx.x * blockDim.x + threadIdx.x;  // 2*8*512*64 threads
  int tg   = idx & 63;           // col group: src cols [8tg, 8tg+7]
  int j    = (idx >> 6) & 511;   // src row
  int b    = (idx >> 15) & 7;    // batch
  int img  = idx >> 18;          // 0=pred, 1=gt
  int lane = tg;                 // wave == one full row; lane == tg
  int wv   = (threadIdx.x >> 6) & 3;

  // Folded color matrix: out[k] = 2 * sum_e v[e] * sum_c awb[2-e][c]*ccm[c][2-k]
  const float* A  = awb + b * 9;
  const float* Cm = ccm + b * 9;
  float M[3][3];
#pragma unroll
  for (int k = 0; k < 3; ++k) {
#pragma unroll
    for (int e = 0; e < 3; ++e) {
      int ar = (2 - e) * 3;
      int cc = 2 - k;
      M[k][e] = 2.0f * (A[ar + 0] * Cm[0 + cc] +
                        A[ar + 1] * Cm[3 + cc] +
                        A[ar + 2] * Cm[6 + cc]);
    }
  }

  int i  = 8 * tg;
  int jm = (j > 0) ? j - 1 : 0;
  int jp = (j < H - 1) ? j + 1 : H - 1;

  const float* src = (img ? gt : pred) + (long long)b * 4 * HW;

  float rT[16], rB[16], gT[16], gB[16], qT[16], qB[16];
  up2_row8(src + 0 * HW, jm, j, jp, i, lane, rT, rB);   // red
  up2_row8(src + 1 * HW, jm, j, jp, i, lane, gT, gB);   // Gr
  up2_row8(src + 2 * HW, jm, j, jp, i, lane, qT, qB);   // Gb
  // Green quad-parity combine: (ee)=avg, (eo)=Gr, (oe)=Gb, (oo)=avg.
#pragma unroll
  for (int p = 0; p < 8; ++p) {
    gT[2 * p]     = 0.5f * (gT[2 * p] + qT[2 * p]);
    /* gT[2p+1] stays Gr */
    gB[2 * p]     = qB[2 * p];
    gB[2 * p + 1] = 0.5f * (gB[2 * p + 1] + qB[2 * p + 1]);
  }
  up2_row8(src + 3 * HW, jm, j, jp, i, lane, qT, qB);   // blue (reuse q)

  int oy = 2 * j;
  float* dst = out + (long long)img * OUT_IMG;
  float* bT = lds[wv][0];
  float* bB = lds[wv][1];
  // Write: lane l owns out cols 16l..16l+15 -> phys base 16l + 4*(l>>2)
  // (16B-aligned; 16 contiguous floats stay within swizzle blocks).
  int wbase = 16 * lane + 4 * (lane >> 2);
  // Read (quarter q): out col 256q+4l -> phys 272q + 4l + 4*(l>>4).
  int rb = 4 * lane + 4 * (lane >> 4);

#pragma unroll
  for (int k = 0; k < 3; ++k) {
    float oT[16], oB[16];
#pragma unroll
    for (int p = 0; p < 16; ++p) {
      oT[p] = gamma_enc(M[k][0] * rT[p] + M[k][1] * gT[p] + M[k][2] * qT[p]);
      oB[p] = gamma_enc(M[k][0] * rB[p] + M[k][1] * gB[p] + M[k][2] * qB[p]);
    }
    // Stage into LDS (swizzled layout; aligned b128 writes).
#pragma unroll
    for (int q = 0; q < 4; ++q) {
      f32x4 vT = {oT[4 * q], oT[4 * q + 1], oT[4 * q + 2], oT[4 * q + 3]};
      f32x4 vB = {oB[4 * q], oB[4 * q + 1], oB[4 * q + 2], oB[4 * q + 3]};
      *reinterpret_cast<f32x4*>(bT + wbase + 4 * q) = vT;
      *reinterpret_cast<f32x4*>(bB + wbase + 4 * q) = vB;
    }
    // Within-wave transpose: wait for own wave's LDS writes (lockstep wave;
    // no cross-wave sharing, so no __syncthreads needed; LDS ops are
    // in-order within a wave, lgkmcnt(0) drains them).
    asm volatile("s_waitcnt lgkmcnt(0)" ::: "memory");
    long long rowbase = ((long long)(b * 3 + k) * 1024 + oy) * 1024;
    // Contiguous 1KB wave stores: store q covers out cols [256q, 256q+256).
#pragma unroll
    for (int q = 0; q < 4; ++q) {
      int rp = rb + 272 * q;
      f32x4 vT = *reinterpret_cast<const f32x4*>(bT + rp);
      f32x4 vB = *reinterpret_cast<const f32x4*>(bB + rp);
      long long so = rowbase + 256 * q + 4 * lane;
      *reinterpret_cast<f32x4*>(dst + so)        = vT;
      *reinterpret_cast<f32x4*>(dst + so + 1024) = vB;
    }
    // Next k reuses the same LDS region: same-wave DS ops stay ordered via
    // the asm memory clobber + in-order LDS completion.
  }
}

extern "C" void kernel_launch(void* const* d_in, const int* in_sizes, int n_in,
                              void* d_out, int out_size, void* d_ws, size_t ws_size,
                              hipStream_t stream) {
  const float* pred = (const float*)d_in[0];
  const float* gt   = (const float*)d_in[1];
  const float* awb  = (const float*)d_in[2];
  const float* ccm  = (const float*)d_in[3];
  // d_in[4] = rgb_gain: unused by the reference.
  float* out = (float*)d_out;

  const int total = 2 * 8 * 512 * 64;  // img * batch * src-rows * col-groups
  dim3 block(256);
  dim3 grid(total / 256);
  isp_kernel<<<grid, block, 0, stream>>>(pred, gt, awb, ccm, out);
}